// Round 12
// baseline (107.916 us; speedup 1.0000x reference)
//
#include <hip/hip_runtime.h>
#include <hip/hip_bf16.h>

#define N_ROWS 4096
#define DIM 512                  // elements AND bytes per fp8 row
#define TWO_N 8192
#define NRB   64                 // 8192 / 128 row-panels
#define NCB   32                 // 8192 / 256 col-panels
#define NBLK  1056               // sum_{by}(32 - (by>>1)) = 8*132

typedef float f32x4 __attribute__((ext_vector_type(4)));
typedef long long ll2 __attribute__((ext_vector_type(2)));

// ---------------------------------------------------------------------------
// async global -> LDS, 16 bytes per lane (wave-uniform LDS base + lane*16)
__device__ inline void g2l16(const void* g, void* l) {
    __builtin_amdgcn_global_load_lds(
        (const __attribute__((address_space(1))) void*)g,
        (__attribute__((address_space(3))) void*)l,
        16, 0, 0);
}

// ---------------------------------------------------------------------------
// Kernel 1: normalize rows; emit fp8-e4m3 z rows in SLOT-PERMUTED order
// (proven v11): within each 128-B K-tile, phys 16-B granule p holds logical
// 8-B slots 8*(p>>2)+(p&3) and +4 -> gemm reads one ds_read_b128 per
// kk-pair at the 0-conflict granule pattern. pos[] stays exact f32.
__global__ void normalize_kernel(const float* __restrict__ ei,
                                 const float* __restrict__ ej,
                                 unsigned char* __restrict__ zq,
                                 float* __restrict__ pos,
                                 float* __restrict__ denom,
                                 float* __restrict__ out) {
    int r = blockIdx.x;          // 0..4095
    int t = threadIdx.x;         // 0..255, 2 dims each
    const float2 vi = ((const float2*)(ei + (size_t)r * DIM))[t];
    const float2 vj = ((const float2*)(ej + (size_t)r * DIM))[t];
    float si  = vi.x * vi.x + vi.y * vi.y;
    float sj  = vj.x * vj.x + vj.y * vj.y;
    float sij = vi.x * vj.x + vi.y * vj.y;

    for (int o = 32; o; o >>= 1) {
        si  += __shfl_down(si, o);
        sj  += __shfl_down(sj, o);
        sij += __shfl_down(sij, o);
    }
    __shared__ float red[3][4];
    int wave = t >> 6, lane = t & 63;
    if (lane == 0) { red[0][wave] = si; red[1][wave] = sj; red[2][wave] = sij; }
    __syncthreads();
    si  = red[0][0] + red[0][1] + red[0][2] + red[0][3];
    sj  = red[1][0] + red[1][1] + red[1][2] + red[1][3];
    sij = red[2][0] + red[2][1] + red[2][2] + red[2][3];

    float rni = 1.0f / fmaxf(sqrtf(si), 1e-12f);
    float rnj = 1.0f / fmaxf(sqrtf(sj), 1e-12f);
    if (t == 0) {
        pos[r] = sij * rni * rnj;
        denom[r] = 0.0f;
        denom[r + N_ROWS] = 0.0f;
        if (r == 0) out[0] = 0.0f;
    }
    int pi8 = __builtin_amdgcn_cvt_pk_fp8_f32(vi.x * rni, vi.y * rni, 0, false);
    int pj8 = __builtin_amdgcn_cvt_pk_fp8_f32(vj.x * rnj, vj.y * rnj, 0, false);

    int kt   = t >> 6;                 // K-tile 0..3 (128 B each)
    int s8   = (t & 63) >> 2;          // logical 8-B slot in tile, 0..15
    int p    = ((s8 >> 3) << 2) | (s8 & 3);   // phys granule 0..7
    int half = (s8 >> 2) & 1;                  // low/high 8 B of granule
    int idx16 = kt * 64 + p * 8 + half * 4 + (t & 3);   // ushort index

    ((unsigned short*)(zq + (size_t)r * DIM))[idx16] = (unsigned short)pi8;
    ((unsigned short*)(zq + (size_t)(r + N_ROWS) * DIM))[idx16] = (unsigned short)pj8;
}

// ---------------------------------------------------------------------------
// Kernel 2 (v12): 128x256-tile fp8 GEMM, strict-upper masking.
//  - Tiles (by 0..63, cx >= by>>1): rows [128by,128by+128), cols
//    [256cx,256cx+256). Every strict-upper cell (c>r) computed exactly
//    once; cells c<=r masked to 0 (covers diag + below-diag overlap).
//    Row-sums -> denom[row], col-sums -> denom[col], unconditionally.
//  - 512 thr / 8 waves (2 row x 4 col), per-wave 64x64 = acc[4][4].
//  - Same 4 K-step drain count as v11 but 2x output/block: drains per
//    output halved; staged bytes/output -25% (A shared across col-halves).
//  - LDS 48 KB -> 3 blocks/CU = 24 waves/CU (+50% TLP vs v11).
//  - Staging chunk + granule swizzle + b128 read pattern byte-identical
//    to PMC-proven v11 (0 bank conflicts).
__global__ __launch_bounds__(512) void gemm_exp_kernel(
        const unsigned char* __restrict__ zq,
        float* __restrict__ denom) {
    // ---- XCD-chunked swizzle (1056 = 8*132), then t -> (by, cx) ----
    const int w = blockIdx.x;
    int t = (w & 7) * (NBLK / 8) + (w >> 3);
    int by = 0;
    while (t >= NCB - (by >> 1)) { t -= NCB - (by >> 1); ++by; }
    const int cx = (by >> 1) + t;

    const int rb = by * 128;             // row base
    const int cb = cx * 256;             // col base

    const int tid  = threadIdx.x;
    const int wave = tid >> 6;           // 0..7
    const int lane = tid & 63;
    const int quad = lane >> 4;          // 0..3
    const int m    = lane & 15;          // 0..15
    const int wm   = (wave >> 2) * 64;   // wave row offset (0/64)
    const int wn   = (wave & 3) * 64;    // wave col offset (0/64/128/192)

    __shared__ __align__(16) unsigned char As[128 * 128];   // 16 KB
    __shared__ __align__(16) unsigned char Bs[256 * 128];   // 32 KB

    f32x4 acc[4][4];
    #pragma unroll
    for (int i = 0; i < 4; ++i)
        #pragma unroll
        for (int j = 0; j < 4; ++j)
            #pragma unroll
            for (int r = 0; r < 4; ++r) acc[i][j][r] = 0.0f;

    // staging: chunk = 1KB = 8 rows x 8 granules(16B). A = 16 chunks,
    // B = 32 chunks. wave w: A chunks 2w,2w+1; B chunks 4w..4w+3.
    // lane l -> row l>>3, phys granule l&7, source granule (l&7)^(l>>3)
    // => LDS phys slot s at row r holds source granule s^(r&7).
    const int srow8 = lane >> 3;
    const int sk    = (((lane & 7) ^ srow8) * 16);   // pre-swizzled src bytes

    for (int it = 0; it < 4; ++it) {     // 4 K-tiles of 128 B
        if (it) __syncthreads();         // readers of previous tile done
        const int k0 = it * 128;         // byte offset in row
        #pragma unroll
        for (int cc = 0; cc < 2; ++cc) { // A chunks
            int c   = 2 * wave + cc;
            int row = c * 8 + srow8;
            g2l16(zq + (size_t)(rb + row) * DIM + k0 + sk, As + c * 1024);
        }
        #pragma unroll
        for (int cc = 0; cc < 4; ++cc) { // B chunks
            int c   = 4 * wave + cc;
            int row = c * 8 + srow8;
            g2l16(zq + (size_t)(cb + row) * DIM + k0 + sk, Bs + c * 1024);
        }
        __syncthreads();                 // implicit vmcnt drain: tile visible

        #pragma unroll
        for (int c = 0; c < 2; ++c) {    // two kk-pairs (kk=2c, 2c+1)
            const int sl = ((((c << 2) | quad) ^ (m & 7)) * 16);
            ll2 af[4], bfr[4];
            #pragma unroll
            for (int i = 0; i < 4; ++i)
                af[i] = *(const ll2*)(As + (wm + i * 16 + m) * 128 + sl);
            #pragma unroll
            for (int j = 0; j < 4; ++j)
                bfr[j] = *(const ll2*)(Bs + (wn + j * 16 + m) * 128 + sl);

            #pragma unroll
            for (int i = 0; i < 4; ++i)
                #pragma unroll
                for (int j = 0; j < 4; ++j) {
                    acc[i][j] = __builtin_amdgcn_mfma_f32_16x16x32_fp8_fp8(
                        af[i][0], bfr[j][0], acc[i][j], 0, 0, 0);
                    acc[i][j] = __builtin_amdgcn_mfma_f32_16x16x32_fp8_fp8(
                        af[i][1], bfr[j][1], acc[i][j], 0, 0, 0);
                }
        }
    }

    // all waves done with final ds_reads before reusing As as scratch
    __syncthreads();

    // ---- epilogue: exp(2*sim), strict-upper mask, row + col sums ----
    float* rs = (float*)As;            // rowsum[128] | colsum[256]
    float* cs = rs + 128;
    if (tid < 128) rs[tid] = 0.0f;
    else if (tid < 384) cs[tid - 128] = 0.0f;
    __syncthreads();

    float colsum[4] = {0.0f, 0.0f, 0.0f, 0.0f};
    #pragma unroll
    for (int i = 0; i < 4; ++i) {
        #pragma unroll
        for (int r = 0; r < 4; ++r) {
            int lrow = wm + i * 16 + quad * 4 + r;    // local row 0..127
            int grow = rb + lrow;
            float s = 0.0f;
            #pragma unroll
            for (int j = 0; j < 4; ++j) {
                int gcol = cb + wn + j * 16 + m;
                float v  = __expf(2.0f * acc[i][j][r]);
                v = (gcol > grow) ? v : 0.0f;         // strict upper only
                s += v;
                colsum[j] += v;
            }
            s += __shfl_xor(s, 1);
            s += __shfl_xor(s, 2);
            s += __shfl_xor(s, 4);
            s += __shfl_xor(s, 8);
            if (m == 0) atomicAdd(&rs[lrow], s);
        }
    }
    #pragma unroll
    for (int j = 0; j < 4; ++j) {
        float s = colsum[j];             // this wave's 64 rows, col wn+j*16+m
        s += __shfl_xor(s, 16);          // combine across quads (rows)
        s += __shfl_xor(s, 32);
        if (quad == 0) atomicAdd(&cs[wn + j * 16 + m], s);
    }
    __syncthreads();
    if (tid < 128)      atomicAdd(&denom[rb + tid], rs[tid]);
    else if (tid < 384) atomicAdd(&denom[cb + tid - 128], cs[tid - 128]);
}

// ---------------------------------------------------------------------------
// Kernel 3: loss (proven, unchanged).
__global__ void loss_kernel(const float* __restrict__ pos,
                            const float* __restrict__ denom,
                            float* __restrict__ out) {
    int r = blockIdx.x * 256 + threadIdx.x;   // 0..8191
    float s = __logf(denom[r]) - 2.0f * pos[r & (N_ROWS - 1)];
    for (int o = 32; o; o >>= 1) s += __shfl_down(s, o);
    __shared__ float red[4];
    int t = threadIdx.x;
    if ((t & 63) == 0) red[t >> 6] = s;
    __syncthreads();
    if (t == 0)
        atomicAdd(out, (red[0] + red[1] + red[2] + red[3]) / (float)TWO_N);
}

// ---------------------------------------------------------------------------
extern "C" void kernel_launch(void* const* d_in, const int* in_sizes, int n_in,
                              void* d_out, int out_size, void* d_ws, size_t ws_size,
                              hipStream_t stream) {
    const float* ei = (const float*)d_in[0];
    const float* ej = (const float*)d_in[1];

    // ws layout: zq (fp8, 2N*D = 4 MB) | pos (N f32) | denom (2N f32)
    unsigned char* zq = (unsigned char*)d_ws;
    float* pos   = (float*)((char*)d_ws + (size_t)TWO_N * DIM);
    float* denom = pos + N_ROWS;
    float* out   = (float*)d_out;

    normalize_kernel<<<N_ROWS, 256, 0, stream>>>(ei, ej, zq, pos, denom, out);
    gemm_exp_kernel<<<NBLK, 512, 0, stream>>>(zq, denom);
    loss_kernel<<<TWO_N / 256, 256, 0, stream>>>(pos, denom, out);
}

// Round 13
// 101.256 us; speedup vs baseline: 1.0658x; 1.0658x over previous
//
#include <hip/hip_runtime.h>
#include <hip/hip_bf16.h>

#define N_ROWS 4096
#define DIM 512                  // elements AND bytes per fp8 row
#define TWO_N 8192
#define NTILE 64                 // 8192 / 128
#define NTRI  (NTILE * (NTILE + 1) / 2)   // 2080 upper-tri 128x128 blocks

typedef float f32x4 __attribute__((ext_vector_type(4)));
typedef long long ll2 __attribute__((ext_vector_type(2)));

// ---------------------------------------------------------------------------
// async global -> LDS, 16 bytes per lane (wave-uniform LDS base + lane*16)
__device__ inline void g2l16(const void* g, void* l) {
    __builtin_amdgcn_global_load_lds(
        (const __attribute__((address_space(1))) void*)g,
        (__attribute__((address_space(3))) void*)l,
        16, 0, 0);
}

// ---------------------------------------------------------------------------
// Kernel 1: normalize rows; emit fp8-e4m3 z rows in SLOT-PERMUTED order:
// within each 128-B K-tile, phys 16-B granule p holds logical 8-B slots
// A = 8*(p>>2)+(p&3) (low half) and A+4 (high half). This lets the gemm
// fetch a lane's kk=2c AND kk=2c+1 fragments with ONE ds_read_b128 at the
// PMC-proven conflict-free granule pattern ((c*4+quad)^(m&7)).
// pos[] stays full f32 (exact positives).
__global__ void normalize_kernel(const float* __restrict__ ei,
                                 const float* __restrict__ ej,
                                 unsigned char* __restrict__ zq,
                                 float* __restrict__ pos,
                                 float* __restrict__ denom,
                                 float* __restrict__ out) {
    int r = blockIdx.x;          // 0..4095
    int t = threadIdx.x;         // 0..255, 2 dims each
    const float2 vi = ((const float2*)(ei + (size_t)r * DIM))[t];
    const float2 vj = ((const float2*)(ej + (size_t)r * DIM))[t];
    float si  = vi.x * vi.x + vi.y * vi.y;
    float sj  = vj.x * vj.x + vj.y * vj.y;
    float sij = vi.x * vj.x + vi.y * vj.y;

    for (int o = 32; o; o >>= 1) {
        si  += __shfl_down(si, o);
        sj  += __shfl_down(sj, o);
        sij += __shfl_down(sij, o);
    }
    __shared__ float red[3][4];
    int wave = t >> 6, lane = t & 63;
    if (lane == 0) { red[0][wave] = si; red[1][wave] = sj; red[2][wave] = sij; }
    __syncthreads();
    si  = red[0][0] + red[0][1] + red[0][2] + red[0][3];
    sj  = red[1][0] + red[1][1] + red[1][2] + red[1][3];
    sij = red[2][0] + red[2][1] + red[2][2] + red[2][3];

    float rni = 1.0f / fmaxf(sqrtf(si), 1e-12f);
    float rnj = 1.0f / fmaxf(sqrtf(sj), 1e-12f);
    if (t == 0) {
        pos[r] = sij * rni * rnj;
        denom[r] = 0.0f;
        denom[r + N_ROWS] = 0.0f;
        if (r == 0) out[0] = 0.0f;
    }
    // pack 2 f32 -> 2 fp8 e4m3 (OCP, RNE); bytes 2t,2t+1 stay adjacent
    // under the slot permutation (slots move whole; 2t,2t+1 share slot).
    int pi8 = __builtin_amdgcn_cvt_pk_fp8_f32(vi.x * rni, vi.y * rni, 0, false);
    int pj8 = __builtin_amdgcn_cvt_pk_fp8_f32(vj.x * rnj, vj.y * rnj, 0, false);

    int kt   = t >> 6;                 // K-tile 0..3 (128 B each)
    int s8   = (t & 63) >> 2;          // logical 8-B slot in tile, 0..15
    int p    = ((s8 >> 3) << 2) | (s8 & 3);   // phys granule 0..7
    int half = (s8 >> 2) & 1;                  // low/high 8 B of granule
    int idx16 = kt * 64 + p * 8 + half * 4 + (t & 3);   // ushort index

    ((unsigned short*)(zq + (size_t)r * DIM))[idx16] = (unsigned short)pi8;
    ((unsigned short*)(zq + (size_t)(r + N_ROWS) * DIM))[idx16] = (unsigned short)pj8;
}

// ---------------------------------------------------------------------------
// Kernel 2 (v11, measured best: gemm ~40.5 us, total 103.8 us):
// 128x128 upper-tri fp8 GEMM. Per K-tile (128 B), per c in {0,1}: ONE
// ds_read_b128 per fragment at phys granule (((c<<2)|quad)^(m&7)) -> low
// 8 B = kk=2c frag, high 8 B = kk=2c+1 frag (permuted zq layout).
// Identical granule pattern to the PMC-proven 0-conflict bf16 kernel.
// XCD-chunked swizzle (R9, +5%); staging: linear LDS dest, pre-swizzled
// global source granule (l&7)^(l>>3).
__global__ __launch_bounds__(256, 4) void gemm_exp_kernel(
        const unsigned char* __restrict__ zq,
        float* __restrict__ denom) {
    // ---- XCD-chunked swizzle (proven R9), then linear -> (by, bx) ----
    const int w = blockIdx.x;
    const int t = (w & 7) * (NTRI / 8) + (w >> 3);
    int by = (int)(0.5f * (2.0f * NTILE + 1.0f -
              sqrtf((2.0f * NTILE + 1.0f) * (2.0f * NTILE + 1.0f) - 8.0f * t)));
    while ((by + 1) * NTILE - ((by + 1) * by) / 2 <= t) ++by;
    while (by * NTILE - (by * (by - 1)) / 2 > t) --by;
    const int bx = by + (t - (by * NTILE - (by * (by - 1)) / 2));

    const int rb = by * 128, cb = bx * 128;
    const bool diag = (rb == cb);

    const int tid  = threadIdx.x;
    const int wave = tid >> 6;
    const int lane = tid & 63;
    const int quad = lane >> 4;          // 0..3
    const int m    = lane & 15;          // 0..15
    const int wm   = (wave >> 1) * 64;   // wave row offset in tile
    const int wn   = (wave & 1) * 64;    // wave col offset in tile

    __shared__ __align__(16) unsigned char As[128 * 128];   // 16 KB
    __shared__ __align__(16) unsigned char Bs[128 * 128];   // 16 KB

    f32x4 acc[4][4];
    #pragma unroll
    for (int i = 0; i < 4; ++i)
        #pragma unroll
        for (int j = 0; j < 4; ++j)
            #pragma unroll
            for (int r = 0; r < 4; ++r) acc[i][j][r] = 0.0f;

    // staging: chunk = 1KB = 8 rows x 8 granules(16B); wave w stages chunks
    // 4w..4w+3 of A and B. lane l -> row l>>3, phys granule l&7, source
    // granule (l&7)^(l>>3)  => LDS phys slot s at row r = source s^(r&7).
    const int srow8 = lane >> 3;
    const int sk    = (((lane & 7) ^ srow8) * 16);   // pre-swizzled src bytes

    for (int it = 0; it < 4; ++it) {     // 4 K-tiles of 128 B
        if (it) __syncthreads();         // readers of previous tile done
        const int k0 = it * 128;         // byte offset in row
        #pragma unroll
        for (int cc = 0; cc < 4; ++cc) {
            int c   = 4 * wave + cc;
            int row = c * 8 + srow8;
            g2l16(zq + (size_t)(rb + row) * DIM + k0 + sk, As + c * 1024);
            g2l16(zq + (size_t)(cb + row) * DIM + k0 + sk, Bs + c * 1024);
        }
        __syncthreads();                 // implicit vmcnt drain: tile visible

        #pragma unroll
        for (int c = 0; c < 2; ++c) {    // two kk-pairs (kk=2c, 2c+1)
            const int sl = ((((c << 2) | quad) ^ (m & 7)) * 16);
            ll2 af[4], bfr[4];
            #pragma unroll
            for (int i = 0; i < 4; ++i)
                af[i] = *(const ll2*)(As + (wm + i * 16 + m) * 128 + sl);
            #pragma unroll
            for (int j = 0; j < 4; ++j)
                bfr[j] = *(const ll2*)(Bs + (wn + j * 16 + m) * 128 + sl);

            #pragma unroll
            for (int i = 0; i < 4; ++i)
                #pragma unroll
                for (int j = 0; j < 4; ++j) {
                    acc[i][j] = __builtin_amdgcn_mfma_f32_16x16x32_fp8_fp8(
                        af[i][0], bfr[j][0], acc[i][j], 0, 0, 0);
                    acc[i][j] = __builtin_amdgcn_mfma_f32_16x16x32_fp8_fp8(
                        af[i][1], bfr[j][1], acc[i][j], 0, 0, 0);
                }
        }
    }

    // all waves done with final ds_reads before reusing As as scratch
    __syncthreads();

    // ---- epilogue: exp(2*sim), mask diag, row sums (+ col sums off-diag) ----
    float* rs = (float*)As;            // rowsum[128] | colsum[128]
    float* cs = rs + 128;
    if (tid < 128) { rs[tid] = 0.0f; cs[tid] = 0.0f; }
    __syncthreads();

    float colsum[4] = {0.0f, 0.0f, 0.0f, 0.0f};
    #pragma unroll
    for (int i = 0; i < 4; ++i) {
        #pragma unroll
        for (int r = 0; r < 4; ++r) {
            int lrow = wm + i * 16 + quad * 4 + r;    // local row 0..127
            int grow = rb + lrow;
            float s = 0.0f;
            #pragma unroll
            for (int j = 0; j < 4; ++j) {
                int gcol = cb + wn + j * 16 + m;
                float v  = __expf(2.0f * acc[i][j][r]);
                v = (grow == gcol) ? 0.0f : v;
                s += v;
                colsum[j] += v;
            }
            s += __shfl_xor(s, 1);
            s += __shfl_xor(s, 2);
            s += __shfl_xor(s, 4);
            s += __shfl_xor(s, 8);
            if (m == 0) atomicAdd(&rs[lrow], s);
        }
    }
    if (!diag) {
        #pragma unroll
        for (int j = 0; j < 4; ++j) {
            float s = colsum[j];       // this wave's 64 rows, col wn+j*16+m
            s += __shfl_xor(s, 16);
            s += __shfl_xor(s, 32);
            if (quad == 0) atomicAdd(&cs[wn + j * 16 + m], s);
        }
    }
    __syncthreads();
    if (tid < 128) {
        atomicAdd(&denom[rb + tid], rs[tid]);
        if (!diag) atomicAdd(&denom[cb + tid], cs[tid]);
    }
}

// ---------------------------------------------------------------------------
// Kernel 3: loss (proven, unchanged).
__global__ void loss_kernel(const float* __restrict__ pos,
                            const float* __restrict__ denom,
                            float* __restrict__ out) {
    int r = blockIdx.x * 256 + threadIdx.x;   // 0..8191
    float s = __logf(denom[r]) - 2.0f * pos[r & (N_ROWS - 1)];
    for (int o = 32; o; o >>= 1) s += __shfl_down(s, o);
    __shared__ float red[4];
    int t = threadIdx.x;
    if ((t & 63) == 0) red[t >> 6] = s;
    __syncthreads();
    if (t == 0)
        atomicAdd(out, (red[0] + red[1] + red[2] + red[3]) / (float)TWO_N);
}

// ---------------------------------------------------------------------------
extern "C" void kernel_launch(void* const* d_in, const int* in_sizes, int n_in,
                              void* d_out, int out_size, void* d_ws, size_t ws_size,
                              hipStream_t stream) {
    const float* ei = (const float*)d_in[0];
    const float* ej = (const float*)d_in[1];

    // ws layout: zq (fp8, 2N*D = 4 MB) | pos (N f32) | denom (2N f32)
    unsigned char* zq = (unsigned char*)d_ws;
    float* pos   = (float*)((char*)d_ws + (size_t)TWO_N * DIM);
    float* denom = pos + N_ROWS;
    float* out   = (float*)d_out;

    normalize_kernel<<<N_ROWS, 256, 0, stream>>>(ei, ej, zq, pos, denom, out);
    gemm_exp_kernel<<<NTRI, 256, 0, stream>>>(zq, denom);
    loss_kernel<<<TWO_N / 256, 256, 0, stream>>>(pos, denom, out);
}